// Round 8
// baseline (30.024 us; speedup 1.0000x reference)
//
#include <hip/hip_runtime.h>
#include <stdint.h>

#define KBOX 1024
#define EPSF 1e-4f
#define SLACK 3e-5f
#define ROWS 8
#define GROUPS (KBOX / ROWS)         // 128
#define TILE_BLOCKS (GROUPS * 4)     // 512: (row-group, 256-col tile)
#define FILL_BLOCKS 2048             // 2048*256 float4 = 2*K*K floats
#define POSE_BLOCKS 4                // 4*256 = 1024 boxes -> hposed output

// ws layout (bytes):
//   0      : bm [K][16] u64    (128 KB) inside bitmask words
//   131072 : tileCnt [K][4] u32 (16 KB)  per (row, col-tile) count
#define BM_OFF 0
#define TC_OFF 131072

// double-precision analytic inverse of the affine 3x4 (rows of A) -> 12 floats
__device__ inline void inv_affine(const float r[12], float o[12]) {
    double m00 = r[0], m01 = r[1], m02 = r[2];
    double m10 = r[4], m11 = r[5], m12 = r[6];
    double m20 = r[8], m21 = r[9], m22 = r[10];
    double c00 = m11 * m22 - m12 * m21;
    double c01 = m12 * m20 - m10 * m22;
    double c02 = m10 * m21 - m11 * m20;
    double det = m00 * c00 + m01 * c01 + m02 * c02;
    double id = 1.0 / det;
    double i00 = c00 * id, i01 = (m02 * m21 - m01 * m22) * id, i02 = (m01 * m12 - m02 * m11) * id;
    double i10 = c01 * id, i11 = (m00 * m22 - m02 * m20) * id, i12 = (m02 * m10 - m00 * m12) * id;
    double i20 = c02 * id, i21 = (m01 * m20 - m00 * m21) * id, i22 = (m00 * m11 - m01 * m10) * id;
    double tx = r[3], ty = r[7], tz = r[11];
    o[0] = (float)i00; o[1] = (float)i01; o[2] = (float)i02;
    o[3] = (float)(-(i00 * tx + i01 * ty + i02 * tz));
    o[4] = (float)i10; o[5] = (float)i11; o[6] = (float)i12;
    o[7] = (float)(-(i10 * tx + i11 * ty + i12 * tz));
    o[8] = (float)i20; o[9] = (float)i21; o[10] = (float)i22;
    o[11] = (float)(-(i20 * tx + i21 * ty + i22 * tz));
}

__global__ void k_main(const float* __restrict__ bbmin, const float* __restrict__ bbmax,
                       const float* __restrict__ A, const uint8_t* __restrict__ disB,
                       float* __restrict__ out_hposed, float4* __restrict__ fillp,
                       uint64_t* __restrict__ bm, uint32_t* __restrict__ tileCnt) {
    int bid = blockIdx.x;
    int t = threadIdx.x;

    if (bid >= TILE_BLOCKS) {
        int b2 = bid - TILE_BLOCKS;
        if (b2 < FILL_BLOCKS) {  // -1 fill of the index region
            fillp[b2 * 256 + t] = make_float4(-1.f, -1.f, -1.f, -1.f);
            return;
        }
        // pose-output blocks: write hposed[...,:3] (output 0)
        int k = (b2 - FILL_BLOCKS) * 256 + t;
        float r[12];
#pragma unroll
        for (int i = 0; i < 3; ++i) {
            float4 a4 = *(const float4*)(A + (size_t)k * 16 + i * 4);
            r[i * 4 + 0] = a4.x; r[i * 4 + 1] = a4.y; r[i * 4 + 2] = a4.z; r[i * 4 + 3] = a4.w;
        }
        float bmn[3], bmx[3];
#pragma unroll
        for (int i = 0; i < 3; ++i) { bmn[i] = bbmin[k * 3 + i]; bmx[i] = bbmax[k * 3 + i]; }
#pragma unroll
        for (int c = 0; c < 8; ++c) {
            float cx = ((c >> 2) & 1) ? bmx[0] : bmn[0];
            float cy = ((c >> 1) & 1) ? bmx[1] : bmn[1];
            float cz = (c & 1) ? bmx[2] : bmn[2];
#pragma unroll
            for (int i = 0; i < 3; ++i)
                out_hposed[(size_t)k * 24 + c * 3 + i] =
                    r[i * 4 + 0] * cx + r[i * 4 + 1] * cy + r[i * 4 + 2] * cz + r[i * 4 + 3];
        }
        return;
    }

    // ---- tile block: rows k0..k0+7, cols j*256..j*256+255 ----
    int g = bid >> 2, j = bid & 3;
    int k0 = g * ROWS;
    if (j * 256 > k0 + ROWS - 1) {  // fully above diagonal: publish zeros, exit
        if (t < ROWS) tileCnt[(k0 + t) * 4 + j] = 0;
        return;
    }
    __shared__ float bk[ROWS][12], hk[ROWS][24];
    __shared__ float bnek[ROWS][3], bxek[ROWS][3], wmnk[ROWS][3], wmxk[ROWS][3];
    __shared__ uint32_t rowCnt[ROWS];
    __shared__ int flagS;
    int lane = t & 63, wave = t >> 6;

    // dis layout detect: wave 0 scans first 256 B (int32 0/1 data has all
    // high bytes zero; random bools don't — false-neg prob 2^-192)
    if (wave == 0) {
        uint32_t dw = ((const uint32_t*)disB)[lane];
        uint64_t b = __ballot((dw & 0xFFFFFF00u) != 0 ? 1 : 0);
        if (lane == 0) flagS = (b != 0ull);
    }
    // 8 spread threads (lanes 16/48 of each wave) prep one row each in parallel
    if ((t & 31) == 16) {
        int r = t >> 5;
        rowCnt[r] = 0;
        int k = k0 + r;
        float rk[12];
#pragma unroll
        for (int i = 0; i < 3; ++i) {
            float4 a4 = *(const float4*)(A + (size_t)k * 16 + i * 4);
            rk[i * 4 + 0] = a4.x; rk[i * 4 + 1] = a4.y; rk[i * 4 + 2] = a4.z; rk[i * 4 + 3] = a4.w;
        }
        inv_affine(rk, bk[r]);
        float bmn[3], bmx[3];
#pragma unroll
        for (int i = 0; i < 3; ++i) { bmn[i] = bbmin[k * 3 + i]; bmx[i] = bbmax[k * 3 + i]; }
#pragma unroll
        for (int i = 0; i < 3; ++i) { bnek[r][i] = bmn[i] + EPSF; bxek[r][i] = bmx[i] - EPSF; }
        float wn[3] = {1e30f, 1e30f, 1e30f}, wx[3] = {-1e30f, -1e30f, -1e30f};
#pragma unroll
        for (int c = 0; c < 8; ++c) {
            float cx = ((c >> 2) & 1) ? bmx[0] : bmn[0];
            float cy = ((c >> 1) & 1) ? bmx[1] : bmn[1];
            float cz = (c & 1) ? bmx[2] : bmn[2];
#pragma unroll
            for (int i = 0; i < 3; ++i) {
                float p = rk[i * 4 + 0] * cx + rk[i * 4 + 1] * cy + rk[i * 4 + 2] * cz + rk[i * 4 + 3];
                hk[r][c * 3 + i] = p;
                wn[i] = fminf(wn[i], p);
                wx[i] = fmaxf(wx[i], p);
            }
        }
#pragma unroll
        for (int i = 0; i < 3; ++i) { wmnk[r][i] = wn[i] - SLACK; wmxk[r][i] = wx[i] + SLACK; }
    }

    // every thread: col box l — affine + bbox + cheap world AABB (|R|·h form)
    int l = j * 256 + t;
    float rl[12];
#pragma unroll
    for (int i = 0; i < 3; ++i) {
        float4 a4 = *(const float4*)(A + (size_t)l * 16 + i * 4);
        rl[i * 4 + 0] = a4.x; rl[i * 4 + 1] = a4.y; rl[i * 4 + 2] = a4.z; rl[i * 4 + 3] = a4.w;
    }
    float bmnl[3], bmxl[3];
#pragma unroll
    for (int i = 0; i < 3; ++i) { bmnl[i] = bbmin[l * 3 + i]; bmxl[i] = bbmax[l * 3 + i]; }
    float wcl[3], whl[3];
    {
        float cx = 0.5f * (bmnl[0] + bmxl[0]), hx = 0.5f * (bmxl[0] - bmnl[0]);
        float cy = 0.5f * (bmnl[1] + bmxl[1]), hy = 0.5f * (bmxl[1] - bmnl[1]);
        float cz = 0.5f * (bmnl[2] + bmxl[2]), hz = 0.5f * (bmxl[2] - bmnl[2]);
#pragma unroll
        for (int i = 0; i < 3; ++i) {
            wcl[i] = rl[i * 4 + 0] * cx + rl[i * 4 + 1] * cy + rl[i * 4 + 2] * cz + rl[i * 4 + 3];
            whl[i] = fabsf(rl[i * 4 + 0]) * hx + fabsf(rl[i * 4 + 1]) * hy + fabsf(rl[i * 4 + 2]) * hz;
        }
    }
    __syncthreads();
    const bool isBool = flagS != 0;

#pragma unroll
    for (int r = 0; r < ROWS; ++r) {
        int k = k0 + r;
        if (j * 256 > k) continue;  // block-uniform: row not covered by this tile
        bool cand = false;
        if (l <= k) {
            cand = (wcl[0] - whl[0] <= wmxk[r][0]) & (wmnk[r][0] <= wcl[0] + whl[0]) &
                   (wcl[1] - whl[1] <= wmxk[r][1]) & (wmnk[r][1] <= wcl[1] + whl[1]) &
                   (wcl[2] - whl[2] <= wmxk[r][2]) & (wmnk[r][2] <= wcl[2] + whl[2]);
        }
        bool bit = false;
        bool dA = false, dB = false;
        if (cand) {  // dis bits only for AABB candidates (~1% of pairs)
            if (isBool) {
                dA = disB[(size_t)k * KBOX + l] != 0;
                dB = disB[(size_t)l * KBOX + k] != 0;
            } else {
                const int* disI = (const int*)disB;
                dA = disI[(size_t)k * KBOX + l] != 0;
                dB = disI[(size_t)l * KBOX + k] != 0;
            }
        }
        if (cand && (dA | dB)) {
            float hl[24];  // corners of l, computed only on this rare path
#pragma unroll
            for (int c = 0; c < 8; ++c) {
                float cx = ((c >> 2) & 1) ? bmxl[0] : bmnl[0];
                float cy = ((c >> 1) & 1) ? bmxl[1] : bmnl[1];
                float cz = (c & 1) ? bmxl[2] : bmnl[2];
#pragma unroll
                for (int i = 0; i < 3; ++i)
                    hl[c * 3 + i] = rl[i * 4 + 0] * cx + rl[i * 4 + 1] * cy +
                                    rl[i * 4 + 2] * cz + rl[i * 4 + 3];
            }
            if (dA) {  // corners of l into frame k
                bool rawA = false;
#pragma unroll
                for (int c = 0; c < 8; ++c) {
                    float px = hl[c * 3 + 0], py = hl[c * 3 + 1], pz = hl[c * 3 + 2];
                    float x = bk[r][0] * px + bk[r][1] * py + bk[r][2] * pz + bk[r][3];
                    float y = bk[r][4] * px + bk[r][5] * py + bk[r][6] * pz + bk[r][7];
                    float z = bk[r][8] * px + bk[r][9] * py + bk[r][10] * pz + bk[r][11];
                    rawA = rawA || (x > bnek[r][0] && x < bxek[r][0] && y > bnek[r][1] &&
                                    y < bxek[r][1] && z > bnek[r][2] && z < bxek[r][2]);
                }
                bit = rawA;
            }
            if (dB && !bit) {  // corners of k into frame l (inverse on demand)
                float bl[12];
                inv_affine(rl, bl);
                bool rawB = false;
#pragma unroll
                for (int c = 0; c < 8; ++c) {
                    float px = hk[r][c * 3 + 0], py = hk[r][c * 3 + 1], pz = hk[r][c * 3 + 2];
                    float x = bl[0] * px + bl[1] * py + bl[2] * pz + bl[3];
                    float y = bl[4] * px + bl[5] * py + bl[6] * pz + bl[7];
                    float z = bl[8] * px + bl[9] * py + bl[10] * pz + bl[11];
                    rawB = rawB || (x > bmnl[0] + EPSF && x < bmxl[0] - EPSF &&
                                    y > bmnl[1] + EPSF && y < bmxl[1] - EPSF &&
                                    z > bmnl[2] + EPSF && z < bmxl[2] - EPSF);
                }
                bit = rawB;
            }
        }
        uint64_t word = __ballot(bit ? 1 : 0);
        if (lane == 0) {
            bm[(size_t)k * 16 + j * 4 + wave] = word;
            if (word) atomicAdd(&rowCnt[r], (uint32_t)__popcll(word));
        }
    }
    __syncthreads();
    if (t < ROWS) tileCnt[(k0 + t) * 4 + j] = rowCnt[t];
}

__global__ void k_compact(const uint64_t* __restrict__ bm,
                          const uint32_t* __restrict__ tileCnt, float* __restrict__ out) {
    int k = blockIdx.x;
    int t = threadIdx.x;  // 256 threads
    int wave = t >> 6, lane = t & 63;
    __shared__ uint32_t ws4[4];
    // start = sum of all tile counts before row k (tiles are row-contiguous)
    uint32_t s = 0;
    for (int idx = t; idx < 4 * k; idx += 256) s += tileCnt[idx];
#pragma unroll
    for (int off = 32; off > 0; off >>= 1) s += __shfl_xor(s, off);
    if (lane == 0) ws4[wave] = s;
    __syncthreads();
    if (t >= 64) return;  // wave 0 finishes the row
    uint32_t start = ws4[0] + ws4[1] + ws4[2] + ws4[3];

    // only words with t*64 <= k are meaningful; mask the rest
    uint64_t w = (t < 16 && t * 64 <= k) ? bm[(size_t)k * 16 + t] : 0ull;
    int c = (int)__popcll(w);
    int p = c;
#pragma unroll
    for (int off = 1; off < 64; off <<= 1) {
        int u = __shfl_up(p, off);
        if (t >= off) p += u;
    }
    int ofs = (int)start + (p - c);
    float fk = (float)k;
    while (w) {
        int b = __builtin_ctzll(w);
        int col = t * 64 + b;
        out[2 * (size_t)ofs + 0] = (float)col;  // min = col (tril => col <= row)
        out[2 * (size_t)ofs + 1] = fk;          // max = row
        ++ofs;
        w &= w - 1;
    }
}

extern "C" void kernel_launch(void* const* d_in, const int* in_sizes, int n_in,
                              void* d_out, int out_size, void* d_ws, size_t ws_size,
                              hipStream_t stream) {
    const float* bbmin = (const float*)d_in[0];
    const float* bbmax = (const float*)d_in[1];
    const float* A = (const float*)d_in[2];
    const uint8_t* dis = (const uint8_t*)d_in[3];
    float* out = (float*)d_out;

    char* ws = (char*)d_ws;
    uint64_t* bm = (uint64_t*)(ws + BM_OFF);
    uint32_t* tileCnt = (uint32_t*)(ws + TC_OFF);

    k_main<<<TILE_BLOCKS + FILL_BLOCKS + POSE_BLOCKS, 256, 0, stream>>>(
        bbmin, bbmax, A, dis, out, (float4*)(out + KBOX * 24), bm, tileCnt);
    k_compact<<<KBOX, 256, 0, stream>>>(bm, tileCnt, out + KBOX * 24);
}